// Round 1
// baseline (922.860 us; speedup 1.0000x reference)
//
#include <hip/hip_runtime.h>

#define N_TOK 262144
#define DDIM  256
#define CCLS  50001

// One thread per 4 contiguous floats of inputs_row; scatter-add into out[t*D+d].
__global__ void scatter_sum_kernel(const float* __restrict__ in,
                                   const int* __restrict__ trow,
                                   float* __restrict__ out) {
    long long idx = (long long)blockIdx.x * blockDim.x + threadIdx.x;
    const long long total4 = (long long)N_TOK * DDIM / 4;
    if (idx >= total4) return;
    const int row = (int)(idx / (DDIM / 4));
    const int d4  = (int)(idx % (DDIM / 4));
    const int t   = trow[row];
    const float4 v = reinterpret_cast<const float4*>(in)[idx];
    float* dst = out + (long long)t * DDIM + d4 * 4;
    atomicAdd(dst + 0, v.x);
    atomicAdd(dst + 1, v.y);
    atomicAdd(dst + 2, v.z);
    atomicAdd(dst + 3, v.w);
}

__global__ void count_kernel(const int* __restrict__ trow,
                             int* __restrict__ counts) {
    int i = blockIdx.x * blockDim.x + threadIdx.x;
    if (i < N_TOK) atomicAdd(&counts[trow[i]], 1);
}

__global__ void present_kernel(const int* __restrict__ tgt, int n,
                               int* __restrict__ present) {
    int i = blockIdx.x * blockDim.x + threadIdx.x;
    if (i < n) present[tgt[i]] = 1;  // benign race: all writers store 1
}

// In-place finalize: out currently holds sums; divide by count if updated,
// else overwrite with center. One thread per 4 elements.
__global__ void finalize_kernel(float* __restrict__ out,
                                const float* __restrict__ center,
                                const int* __restrict__ counts,
                                const int* __restrict__ present) {
    long long idx = (long long)blockIdx.x * blockDim.x + threadIdx.x;
    const long long total4 = (long long)CCLS * DDIM / 4;
    if (idx >= total4) return;
    const int c = (int)(idx / (DDIM / 4));
    const int cnt = counts[c];
    const bool upd = (present[c] != 0) && (cnt > 0);
    float4 o = reinterpret_cast<float4*>(out)[idx];
    const float4 cen = reinterpret_cast<const float4*>(center)[idx];
    if (upd) {
        const float fc = (float)cnt;
        o.x = o.x / fc;
        o.y = o.y / fc;
        o.z = o.z / fc;
        o.w = o.w / fc;
    } else {
        o = cen;
    }
    reinterpret_cast<float4*>(out)[idx] = o;
}

extern "C" void kernel_launch(void* const* d_in, const int* in_sizes, int n_in,
                              void* d_out, int out_size, void* d_ws, size_t ws_size,
                              hipStream_t stream) {
    const float* inputs_row = (const float*)d_in[0];
    const float* center     = (const float*)d_in[1];
    const int*   target_row = (const int*)d_in[2];
    const int*   target     = (const int*)d_in[3];
    const int    n_target   = in_sizes[3];

    float* out = (float*)d_out;
    int* counts  = (int*)d_ws;
    int* present = counts + CCLS;

    // Zero the sums accumulator (d_out) and counts/present scratch.
    hipMemsetAsync(d_out, 0, (size_t)CCLS * DDIM * sizeof(float), stream);
    hipMemsetAsync(d_ws, 0, (size_t)2 * CCLS * sizeof(int), stream);

    // Scatter-add sums.
    {
        const long long total4 = (long long)N_TOK * DDIM / 4;
        const int block = 256;
        const int grid = (int)((total4 + block - 1) / block);
        scatter_sum_kernel<<<grid, block, 0, stream>>>(inputs_row, target_row, out);
    }
    // Counts.
    {
        const int block = 256;
        const int grid = (N_TOK + block - 1) / block;
        count_kernel<<<grid, block, 0, stream>>>(target_row, counts);
    }
    // Present flags.
    {
        const int block = 256;
        const int grid = (n_target + block - 1) / block;
        present_kernel<<<grid, block, 0, stream>>>(target, n_target, present);
    }
    // Finalize.
    {
        const long long total4 = (long long)CCLS * DDIM / 4;
        const int block = 256;
        const int grid = (int)((total4 + block - 1) / block);
        finalize_kernel<<<grid, block, 0, stream>>>(out, center, counts, present);
    }
}

// Round 2
// 51.496 us; speedup vs baseline: 17.9212x; 17.9212x over previous
//
#include <hip/hip_runtime.h>

#define N_TOK 262144
#define DDIM  256
#define CCLS  50001
#define SCAN_BLOCK 1024
#define NSCAN_BLOCKS ((CCLS + SCAN_BLOCK - 1) / SCAN_BLOCK)   // 49

// present[target[i]] = 1
__global__ void present_kernel(const int* __restrict__ tgt, int n,
                               int* __restrict__ present) {
    int i = blockIdx.x * blockDim.x + threadIdx.x;
    if (i < n) present[tgt[i]] = 1;  // benign race: all writers store 1
}

// counts[t] += 1 only for rows whose class is present (others can never update)
__global__ void count_kernel(const int* __restrict__ trow,
                             const int* __restrict__ present,
                             int* __restrict__ counts) {
    int i = blockIdx.x * blockDim.x + threadIdx.x;
    if (i < N_TOK) {
        int t = trow[i];
        if (present[t]) atomicAdd(&counts[t], 1);
    }
}

// Per-block inclusive scan (Hillis-Steele in LDS); writes block-exclusive
// offsets and the block total.
__global__ void scan_blocks(const int* __restrict__ counts,
                            int* __restrict__ offsets,
                            int* __restrict__ block_tot) {
    __shared__ int sm[SCAN_BLOCK];
    int i = blockIdx.x * SCAN_BLOCK + threadIdx.x;
    int v = (i < CCLS) ? counts[i] : 0;
    sm[threadIdx.x] = v;
    __syncthreads();
    int acc = v;
    for (int off = 1; off < SCAN_BLOCK; off <<= 1) {
        int t = (threadIdx.x >= (unsigned)off) ? sm[threadIdx.x - off] : 0;
        __syncthreads();
        acc += t;
        sm[threadIdx.x] = acc;
        __syncthreads();
    }
    if (i < CCLS) offsets[i] = acc - v;  // exclusive within block
    if (threadIdx.x == SCAN_BLOCK - 1) block_tot[blockIdx.x] = acc;
}

// Exclusive scan of the (<=64, zero-padded) block totals in one wave.
__global__ void scan_totals(int* __restrict__ block_tot) {
    int lane = threadIdx.x;           // 64 threads
    int v = block_tot[lane];          // entries >= NSCAN_BLOCKS were zeroed
    int orig = v;
    for (int off = 1; off < 64; off <<= 1) {
        int t = __shfl_up(v, off);
        if (lane >= off) v += t;
    }
    block_tot[lane] = v - orig;       // exclusive
}

__global__ void add_block_offsets(int* __restrict__ offsets,
                                  const int* __restrict__ block_tot) {
    int i = blockIdx.x * SCAN_BLOCK + threadIdx.x;
    if (i < CCLS) offsets[i] += block_tot[blockIdx.x];
}

// Scatter row indices into perm, bucketed by class. offsets[t] is advanced by
// atomicAdd; after this kernel offsets[t] == bucket_end(t).
__global__ void scatter_kernel(const int* __restrict__ trow,
                               const int* __restrict__ present,
                               int* __restrict__ offsets,
                               int* __restrict__ perm) {
    int i = blockIdx.x * blockDim.x + threadIdx.x;
    if (i < N_TOK) {
        int t = trow[i];
        if (present[t]) {
            int p = atomicAdd(&offsets[t], 1);
            perm[p] = i;
        }
    }
}

// One wave per class: gather+sum its rows (coalesced 1KB/row) and write the
// final output (mean if updated, else center). Fuses the finalize.
__global__ void out_kernel(const float* __restrict__ in,
                           const float* __restrict__ center,
                           const int* __restrict__ counts,
                           const int* __restrict__ present,
                           const int* __restrict__ offsets,   // now bucket ends
                           const int* __restrict__ perm,
                           float* __restrict__ out) {
    const int wid  = threadIdx.x >> 6;          // 4 waves/block
    const int lane = threadIdx.x & 63;
    const int c = blockIdx.x * 4 + wid;
    if (c >= CCLS) return;

    const int cnt = counts[c];
    const bool upd = (present[c] != 0) && (cnt > 0);
    const long long o4 = (long long)c * (DDIM / 4) + lane;  // float4 index

    float4 r;
    if (upd) {
        const int base = offsets[c] - cnt;      // offsets[c] is bucket end
        float4 acc = {0.f, 0.f, 0.f, 0.f};
        for (int k = 0; k < cnt; ++k) {
            const int row = perm[base + k];
            const float4 v =
                reinterpret_cast<const float4*>(in)[(long long)row * (DDIM / 4) + lane];
            acc.x += v.x; acc.y += v.y; acc.z += v.z; acc.w += v.w;
        }
        const float inv = 1.0f / (float)cnt;
        r.x = acc.x * inv; r.y = acc.y * inv; r.z = acc.z * inv; r.w = acc.w * inv;
    } else {
        r = reinterpret_cast<const float4*>(center)[o4];
    }
    reinterpret_cast<float4*>(out)[o4] = r;
}

extern "C" void kernel_launch(void* const* d_in, const int* in_sizes, int n_in,
                              void* d_out, int out_size, void* d_ws, size_t ws_size,
                              hipStream_t stream) {
    const float* inputs_row = (const float*)d_in[0];
    const float* center     = (const float*)d_in[1];
    const int*   target_row = (const int*)d_in[2];
    const int*   target     = (const int*)d_in[3];
    const int    n_target   = in_sizes[3];

    float* out = (float*)d_out;

    // ws layout (ints): counts[CCLS] | present[CCLS] | block_tot[64] |
    //                   offsets[CCLS] | perm[N_TOK]
    int* counts    = (int*)d_ws;
    int* present   = counts + CCLS;
    int* block_tot = present + CCLS;
    int* offsets   = block_tot + 64;
    int* perm      = offsets + CCLS;

    // Zero counts + present + block_tot (offsets/perm fully overwritten).
    hipMemsetAsync(d_ws, 0, (size_t)(2 * CCLS + 64) * sizeof(int), stream);

    present_kernel<<<(n_target + 255) / 256, 256, 0, stream>>>(target, n_target, present);
    count_kernel<<<(N_TOK + 255) / 256, 256, 0, stream>>>(target_row, present, counts);
    scan_blocks<<<NSCAN_BLOCKS, SCAN_BLOCK, 0, stream>>>(counts, offsets, block_tot);
    scan_totals<<<1, 64, 0, stream>>>(block_tot);
    add_block_offsets<<<NSCAN_BLOCKS, SCAN_BLOCK, 0, stream>>>(offsets, block_tot);
    scatter_kernel<<<(N_TOK + 255) / 256, 256, 0, stream>>>(target_row, present, offsets, perm);

    const int out_blocks = (CCLS + 3) / 4;     // 4 classes (waves) per block
    out_kernel<<<out_blocks, 256, 0, stream>>>(inputs_row, center, counts, present,
                                               offsets, perm, out);
}

// Round 3
// 44.764 us; speedup vs baseline: 20.6160x; 1.1504x over previous
//
#include <hip/hip_runtime.h>

#define N_TOK 262144
#define DDIM  256
#define CCLS  50001

// K1: heads = -1, present = 0.
__global__ void init_kernel(int* __restrict__ heads, int* __restrict__ present) {
    int i = blockIdx.x * blockDim.x + threadIdx.x;
    if (i < CCLS) {
        heads[i] = -1;
        present[i] = 0;
    }
}

// K2: build per-class linked lists over ALL rows (no filter -> no dependency
// on present), and scatter present flags (nothing here reads present, so the
// two writes can share a kernel).
__global__ void build_kernel(const int* __restrict__ trow,
                             const int* __restrict__ tgt, int n_tgt,
                             int* __restrict__ heads,
                             int* __restrict__ next,
                             int* __restrict__ present) {
    int i = blockIdx.x * blockDim.x + threadIdx.x;
    if (i < N_TOK) {
        const int t = trow[i];
        const int old = atomicExch(&heads[t], i);
        next[i] = old;                    // coalesced 1 MB write
    }
    if (i < n_tgt) present[tgt[i]] = 1;   // benign race: all store 1
}

// K3: one wave per class. Updated classes traverse their list (count during
// traversal), sum rows in registers (lane = one float4 of the row), write
// mean. Non-updated classes stream-copy center.
__global__ void out_kernel(const float* __restrict__ in,
                           const float* __restrict__ center,
                           const int* __restrict__ heads,
                           const int* __restrict__ next,
                           const int* __restrict__ present,
                           float* __restrict__ out) {
    const int wid  = threadIdx.x >> 6;          // 4 waves/block
    const int lane = threadIdx.x & 63;
    const int c = blockIdx.x * 4 + wid;
    if (c >= CCLS) return;

    const int head = heads[c];
    const bool upd = (present[c] != 0) && (head != -1);
    const long long o4 = (long long)c * (DDIM / 4) + lane;  // float4 index

    float4 r;
    if (upd) {
        float4 acc = {0.f, 0.f, 0.f, 0.f};
        int cnt = 0;
        for (int row = head; row != -1; row = next[row]) {
            const float4 v =
                reinterpret_cast<const float4*>(in)[(long long)row * (DDIM / 4) + lane];
            acc.x += v.x; acc.y += v.y; acc.z += v.z; acc.w += v.w;
            ++cnt;
        }
        const float inv = 1.0f / (float)cnt;
        r.x = acc.x * inv; r.y = acc.y * inv; r.z = acc.z * inv; r.w = acc.w * inv;
    } else {
        r = reinterpret_cast<const float4*>(center)[o4];
    }
    reinterpret_cast<float4*>(out)[o4] = r;
}

extern "C" void kernel_launch(void* const* d_in, const int* in_sizes, int n_in,
                              void* d_out, int out_size, void* d_ws, size_t ws_size,
                              hipStream_t stream) {
    const float* inputs_row = (const float*)d_in[0];
    const float* center     = (const float*)d_in[1];
    const int*   target_row = (const int*)d_in[2];
    const int*   target     = (const int*)d_in[3];
    const int    n_target   = in_sizes[3];

    float* out = (float*)d_out;

    // ws layout (ints): heads[CCLS] | present[CCLS] | next[N_TOK]
    int* heads   = (int*)d_ws;
    int* present = heads + CCLS;
    int* next    = present + CCLS;

    init_kernel<<<(CCLS + 255) / 256, 256, 0, stream>>>(heads, present);
    build_kernel<<<(N_TOK + 255) / 256, 256, 0, stream>>>(target_row, target, n_target,
                                                          heads, next, present);
    out_kernel<<<(CCLS + 3) / 4, 256, 0, stream>>>(inputs_row, center, heads, next,
                                                   present, out);
}